// Round 1
// baseline (2929.246 us; speedup 1.0000x reference)
//
#include <hip/hip_runtime.h>

#define D 128

// ---------------- degree count ----------------
__global__ void count_edges(const int* __restrict__ e, int E, int* __restrict__ cnt) {
    int i = blockIdx.x * 256 + threadIdx.x;
    if (i < E) {
        int u = e[i];
        int v = e[E + i];
        atomicAdd(&cnt[u], 1);
        atomicAdd(&cnt[v], 1);
    }
}

__global__ void compute_invsqrt(const int* __restrict__ cnt, float* __restrict__ invs, int n) {
    int i = blockIdx.x * 256 + threadIdx.x;
    if (i < n) invs[i] = rsqrtf((float)(cnt[i] + 1));  // +1 self loop
}

// ---------------- exclusive scan (2-level) ----------------
__global__ void scan_block(const int* __restrict__ cnt, int* __restrict__ excl,
                           int* __restrict__ bsums, int n) {
    __shared__ int sm[256];
    int i = blockIdx.x * 256 + threadIdx.x;
    int v = (i < n) ? cnt[i] : 0;
    sm[threadIdx.x] = v;
    __syncthreads();
    for (int off = 1; off < 256; off <<= 1) {
        int t = (threadIdx.x >= off) ? sm[threadIdx.x - off] : 0;
        __syncthreads();
        sm[threadIdx.x] += t;
        __syncthreads();
    }
    if (i < n) excl[i] = sm[threadIdx.x] - v;
    if (threadIdx.x == 255) bsums[blockIdx.x] = sm[255];
}

__global__ void scan_bsums(int* __restrict__ bsums, int nb) {
    __shared__ int sm[512];
    int t = threadIdx.x;
    int v = (t < nb) ? bsums[t] : 0;
    sm[t] = v;
    __syncthreads();
    for (int off = 1; off < 512; off <<= 1) {
        int x = (t >= off) ? sm[t - off] : 0;
        __syncthreads();
        sm[t] += x;
        __syncthreads();
    }
    if (t < nb) bsums[t] = sm[t] - v;  // exclusive
}

__global__ void add_offsets(int* __restrict__ rowptr, int* __restrict__ cursor,
                            const int* __restrict__ bsums, int n, int total) {
    int i = blockIdx.x * 256 + threadIdx.x;
    if (i < n) {
        int v = rowptr[i] + bsums[blockIdx.x];
        rowptr[i] = v;
        cursor[i] = v;
    }
    if (i == 0) rowptr[n] = total;
}

// ---------------- CSR fill ----------------
__global__ void fill_csr(const int* __restrict__ e, int E, int* __restrict__ cursor,
                         int* __restrict__ col) {
    int i = blockIdx.x * 256 + threadIdx.x;
    if (i < E) {
        int u = e[i];
        int v = e[E + i];
        int p1 = atomicAdd(&cursor[v], 1);
        col[p1] = u;
        int p2 = atomicAdd(&cursor[u], 1);
        col[p2] = v;
    }
}

// ---------------- pull aggregation: one wave per node ----------------
__global__ __launch_bounds__(256) void pull_agg(const float* __restrict__ h,
                                                const int* __restrict__ rowptr,
                                                const int* __restrict__ col,
                                                const float* __restrict__ invs,
                                                float* __restrict__ agg, int n) {
    int gw = (blockIdx.x * 256 + threadIdx.x) >> 6;  // global wave id = node
    if (gw >= n) return;
    int lane = threadIdx.x & 63;
    const float2* hp = (const float2*)h;
    float inv_n = invs[gw];
    size_t rowbase = (size_t)gw * 64;
    float2 hv = hp[rowbase + lane];
    // accumulate sum_s h[s]*inv_s  (self-loop folded in with inv_n), scale by inv_n at end
    float ax = hv.x * inv_n;
    float ay = hv.y * inv_n;
    int beg = rowptr[gw];
    int end = rowptr[gw + 1];
    for (int j = beg; j < end; ++j) {
        int s = col[j];
        float is = invs[s];
        float2 hs = hp[(size_t)s * 64 + lane];
        ax = fmaf(hs.x, is, ax);
        ay = fmaf(hs.y, is, ay);
    }
    float2 o;
    o.x = ax * inv_n;
    o.y = ay * inv_n;
    ((float2*)agg)[rowbase + lane] = o;
}

// ---------------- fused  O = relu(A @ W) + R ----------------
// A:[n,128] W:[128,128] row-major, R residual, O out (may alias R).
// block = 256 threads, 32 rows per block. W (64KB) + A-tile (16KB) in dynamic LDS.
__global__ __launch_bounds__(256) void gemm_relu_res(const float* __restrict__ A,
                                                     const float* __restrict__ W,
                                                     const float* __restrict__ R,
                                                     float* __restrict__ O, int n) {
    extern __shared__ float smem[];
    float* Wl = smem;            // 128*128
    float* Al = smem + 128 * 128;  // 32*128
    int tid = threadIdx.x;
    // stage W: 4096 float4
    for (int idx = tid; idx < 4096; idx += 256) {
        ((float4*)Wl)[idx] = ((const float4*)W)[idx];
    }
    int row0 = blockIdx.x * 32;
    // stage A tile: 1024 float4
    for (int idx = tid; idx < 1024; idx += 256) {
        int r = idx >> 5;
        int c4 = idx & 31;
        float4 v;
        if (row0 + r < n)
            v = ((const float4*)(A + (size_t)(row0 + r) * 128))[c4];
        else
            v = make_float4(0.f, 0.f, 0.f, 0.f);
        ((float4*)Al)[idx] = v;
    }
    __syncthreads();

    int c = tid & 127;
    int rg = tid >> 7;  // 0 or 1 -> rows rg*16 .. rg*16+15
    float acc[16];
#pragma unroll
    for (int rr = 0; rr < 16; ++rr) acc[rr] = 0.f;

    for (int k4 = 0; k4 < 128; k4 += 4) {
        float w0 = Wl[(k4 + 0) * 128 + c];
        float w1 = Wl[(k4 + 1) * 128 + c];
        float w2 = Wl[(k4 + 2) * 128 + c];
        float w3 = Wl[(k4 + 3) * 128 + c];
#pragma unroll
        for (int rr = 0; rr < 16; ++rr) {
            const float4 a = *((const float4*)&Al[(rg * 16 + rr) * 128 + k4]);
            acc[rr] = fmaf(a.x, w0, fmaf(a.y, w1, fmaf(a.z, w2, fmaf(a.w, w3, acc[rr]))));
        }
    }

#pragma unroll
    for (int rr = 0; rr < 16; ++rr) {
        int r = row0 + rg * 16 + rr;
        if (r < n) {
            size_t off = (size_t)r * 128 + c;
            float v = acc[rr];
            v = v > 0.f ? v : 0.f;
            O[off] = v + R[off];
        }
    }
}

// ---------------- seed gather ----------------
__global__ void gather_seeds(const int* __restrict__ seeds, const float* __restrict__ ent,
                             float* __restrict__ out, int S) {
    int idx = blockIdx.x * 256 + threadIdx.x;
    if (idx < S * 32) {
        int i = idx >> 5;
        int t = idx & 31;
        int s = seeds[i];
        ((float4*)out)[(size_t)i * 32 + t] = ((const float4*)ent)[(size_t)s * 32 + t];
    }
}

// ---------------- per-graph driver ----------------
static void run_graph(const int* edges, const float* emb, const float* W0, const float* W1,
                      float* ent_out, float* agg, float* invs, int* cnt, int* rowptr,
                      int* cursor, int* bsums, int* colb, int N, int E, hipStream_t stream) {
    hipMemsetAsync(cnt, 0, (size_t)N * 4, stream);
    int eb = (E + 255) / 256;
    int nb = (N + 255) / 256;
    count_edges<<<eb, 256, 0, stream>>>(edges, E, cnt);
    compute_invsqrt<<<nb, 256, 0, stream>>>(cnt, invs, N);
    scan_block<<<nb, 256, 0, stream>>>(cnt, rowptr, bsums, N);
    scan_bsums<<<1, 512, 0, stream>>>(bsums, nb);
    add_offsets<<<nb, 256, 0, stream>>>(rowptr, cursor, bsums, N, 2 * E);
    fill_csr<<<eb, 256, 0, stream>>>(edges, E, cursor, colb);

    int pb = (N + 3) / 4;  // 4 waves (nodes) per 256-thread block
    int gb = (N + 31) / 32;
    size_t shbytes = (128 * 128 + 32 * 128) * sizeof(float);  // 80KB
    // layer 1: agg from emb, ent_out = relu(agg@W0)+emb
    pull_agg<<<pb, 256, 0, stream>>>(emb, rowptr, colb, invs, agg, N);
    gemm_relu_res<<<gb, 256, shbytes, stream>>>(agg, W0, emb, ent_out, N);
    // layer 2: agg from ent_out, ent_out = relu(agg@W1)+ent_out (in-place, per-element)
    pull_agg<<<pb, 256, 0, stream>>>(ent_out, rowptr, colb, invs, agg, N);
    gemm_relu_res<<<gb, 256, shbytes, stream>>>(agg, W1, ent_out, ent_out, N);
}

extern "C" void kernel_launch(void* const* d_in, const int* in_sizes, int n_in,
                              void* d_out, int out_size, void* d_ws, size_t ws_size,
                              hipStream_t stream) {
    const int* seeds_sr = (const int*)d_in[0];
    const int* seeds_tg = (const int*)d_in[1];
    const int* edges_sr = (const int*)d_in[2];
    const int* edges_tg = (const int*)d_in[3];
    const float* emb_sr = (const float*)d_in[4];
    const float* emb_tg = (const float*)d_in[5];
    const float* W0 = (const float*)d_in[6];
    const float* W1 = (const float*)d_in[7];

    int S = in_sizes[0];
    int E = in_sizes[2] / 2;
    int N = in_sizes[4] / D;

    float* out = (float*)d_out;
    float* out_sr_seed = out;
    float* out_tg_seed = out + (size_t)S * D;
    float* out_sr_ent = out + 2 * (size_t)S * D;
    float* out_tg_ent = out_sr_ent + (size_t)N * D;

    // workspace carve-up
    char* w = (char*)d_ws;
    float* agg = (float*)w;      w += (size_t)N * D * 4;
    float* invs = (float*)w;     w += (size_t)N * 4;
    int* cnt = (int*)w;          w += (size_t)N * 4;
    int* rowptr = (int*)w;       w += (size_t)(N + 4) * 4;
    int* cursor = (int*)w;       w += (size_t)N * 4;
    int* bsums = (int*)w;        w += 4096;
    int* colb = (int*)w;         // 2*E ints

    run_graph(edges_sr, emb_sr, W0, W1, out_sr_ent, agg, invs, cnt, rowptr, cursor, bsums,
              colb, N, E, stream);
    run_graph(edges_tg, emb_tg, W0, W1, out_tg_ent, agg, invs, cnt, rowptr, cursor, bsums,
              colb, N, E, stream);

    int sb = (S * 32 + 255) / 256;
    gather_seeds<<<sb, 256, 0, stream>>>(seeds_sr, out_sr_ent, out_sr_seed, S);
    gather_seeds<<<sb, 256, 0, stream>>>(seeds_tg, out_tg_ent, out_tg_seed, S);
}

// Round 2
// 2219.747 us; speedup vs baseline: 1.3196x; 1.3196x over previous
//
#include <hip/hip_runtime.h>

#define D 128

typedef unsigned int u32;
typedef unsigned short u16;

__device__ __forceinline__ float bflo(u32 u) { return __uint_as_float(u << 16); }
__device__ __forceinline__ float bfhi(u32 u) { return __uint_as_float(u & 0xffff0000u); }
__device__ __forceinline__ u16 f2bf(float x) {
    u32 u = __float_as_uint(x);
    u = (u + 0x7fffu + ((u >> 16) & 1u)) >> 16;  // round-to-nearest-even
    return (u16)u;
}
__device__ __forceinline__ u32 pack2bf(float a, float b) {
    return (u32)f2bf(a) | ((u32)f2bf(b) << 16);
}

// ---------------- degree count ----------------
__global__ void count_edges(const int* __restrict__ e, int E, int* __restrict__ cnt) {
    int i = blockIdx.x * 256 + threadIdx.x;
    if (i < E) {
        int u = e[i];
        int v = e[E + i];
        atomicAdd(&cnt[u], 1);
        atomicAdd(&cnt[v], 1);
    }
}

__global__ void compute_invsqrt(const int* __restrict__ cnt, float* __restrict__ invs, int n) {
    int i = blockIdx.x * 256 + threadIdx.x;
    if (i < n) invs[i] = rsqrtf((float)(cnt[i] + 1));  // +1 self loop
}

// ---------------- exclusive scan (2-level) ----------------
__global__ void scan_block(const int* __restrict__ cnt, int* __restrict__ excl,
                           int* __restrict__ bsums, int n) {
    __shared__ int sm[256];
    int i = blockIdx.x * 256 + threadIdx.x;
    int v = (i < n) ? cnt[i] : 0;
    sm[threadIdx.x] = v;
    __syncthreads();
    for (int off = 1; off < 256; off <<= 1) {
        int t = (threadIdx.x >= off) ? sm[threadIdx.x - off] : 0;
        __syncthreads();
        sm[threadIdx.x] += t;
        __syncthreads();
    }
    if (i < n) excl[i] = sm[threadIdx.x] - v;
    if (threadIdx.x == 255) bsums[blockIdx.x] = sm[255];
}

__global__ void scan_bsums(int* __restrict__ bsums, int nb) {
    __shared__ int sm[512];
    int t = threadIdx.x;
    int v = (t < nb) ? bsums[t] : 0;
    sm[t] = v;
    __syncthreads();
    for (int off = 1; off < 512; off <<= 1) {
        int x = (t >= off) ? sm[t - off] : 0;
        __syncthreads();
        sm[t] += x;
        __syncthreads();
    }
    if (t < nb) bsums[t] = sm[t] - v;  // exclusive
}

__global__ void add_offsets(int* __restrict__ rowptr, int* __restrict__ cursor,
                            const int* __restrict__ bsums, int n, int total) {
    int i = blockIdx.x * 256 + threadIdx.x;
    if (i < n) {
        int v = rowptr[i] + bsums[blockIdx.x];
        rowptr[i] = v;
        cursor[i] = v;
    }
    if (i == 0) rowptr[n] = total;
}

// ---------------- CSR fill ----------------
__global__ void fill_csr(const int* __restrict__ e, int E, int* __restrict__ cursor,
                         int* __restrict__ col) {
    int i = blockIdx.x * 256 + threadIdx.x;
    if (i < E) {
        int u = e[i];
        int v = e[E + i];
        int p1 = atomicAdd(&cursor[v], 1);
        col[p1] = u;
        int p2 = atomicAdd(&cursor[u], 1);
        col[p2] = v;
    }
}

// ---------------- cast + pre-scale: hb[i] = bf16(h[i] * invs[row]) ----------------
__global__ void cast_scale_bf16(const float* __restrict__ h, const float* __restrict__ invs,
                                u32* __restrict__ hb, int n64) {
    int idx = blockIdx.x * 256 + threadIdx.x;
    if (idx >= n64) return;
    int row = idx >> 6;
    float is = invs[row];
    float2 v = ((const float2*)h)[idx];
    hb[idx] = pack2bf(v.x * is, v.y * is);
}

// ---------------- pull aggregation: one wave per node, bf16 pre-scaled gather --------
// agg_b (bf16 packed, pre-scaled rows) <- inv_n * ( h_self*inv_n + sum_s hb[s] )
__global__ __launch_bounds__(256) void pull_agg(const float* __restrict__ hself,
                                                const u32* __restrict__ hb,
                                                const int* __restrict__ rowptr,
                                                const int* __restrict__ col,
                                                const float* __restrict__ invs,
                                                u32* __restrict__ aggb, int n) {
    int gw = (blockIdx.x * 256 + threadIdx.x) >> 6;  // global wave id = node
    if (gw >= n) return;
    int lane = threadIdx.x & 63;
    float inv_n = invs[gw];
    size_t rowbase = (size_t)gw * 64;
    float2 hv = ((const float2*)hself)[rowbase + lane];
    float ax = hv.x * inv_n;
    float ay = hv.y * inv_n;
    int j = rowptr[gw];
    int end = rowptr[gw + 1];
    for (; j + 4 <= end; j += 4) {
        int s0 = col[j], s1 = col[j + 1], s2 = col[j + 2], s3 = col[j + 3];
        u32 u0 = hb[(size_t)s0 * 64 + lane];
        u32 u1 = hb[(size_t)s1 * 64 + lane];
        u32 u2 = hb[(size_t)s2 * 64 + lane];
        u32 u3 = hb[(size_t)s3 * 64 + lane];
        ax += (bflo(u0) + bflo(u1)) + (bflo(u2) + bflo(u3));
        ay += (bfhi(u0) + bfhi(u1)) + (bfhi(u2) + bfhi(u3));
    }
    for (; j < end; ++j) {
        int s = col[j];
        u32 u = hb[(size_t)s * 64 + lane];
        ax += bflo(u);
        ay += bfhi(u);
    }
    aggb[rowbase + lane] = pack2bf(ax * inv_n, ay * inv_n);
}

// ---------------- fused  O = relu(unpack(Ab) @ W) + R, optional bf16 writeback -------
// Ab: [n,64] packed bf16 pairs. W:[128,128] fp32 row-major. R fp32 residual.
// O fp32 out. If WRITE_BF16: hb[r] = bf16(O[r] * invs[r]) (gather source for next pull).
template <int WRITE_BF16>
__global__ __launch_bounds__(256) void gemm_relu_res(const u32* __restrict__ Ab,
                                                     const float* __restrict__ W,
                                                     const float* __restrict__ R,
                                                     const float* __restrict__ invs,
                                                     float* __restrict__ O,
                                                     u16* __restrict__ hb, int n) {
    extern __shared__ float smem[];
    float* Wl = smem;              // 128*128 fp32
    float* Al = smem + 128 * 128;  // 32*128 fp32
    int tid = threadIdx.x;
    // stage W: 4096 float4
    for (int idx = tid; idx < 4096; idx += 256) {
        ((float4*)Wl)[idx] = ((const float4*)W)[idx];
    }
    int row0 = blockIdx.x * 32;
    // stage + unpack A tile: 2048 packed u32 -> 32x128 fp32
    for (int idx = tid; idx < 2048; idx += 256) {
        int r = idx >> 6;
        int p = idx & 63;
        u32 u = (row0 + r < n) ? Ab[(size_t)(row0 + r) * 64 + p] : 0u;
        Al[r * 128 + 2 * p] = bflo(u);
        Al[r * 128 + 2 * p + 1] = bfhi(u);
    }
    __syncthreads();

    int c = tid & 127;
    int rg = tid >> 7;  // 0 or 1 -> rows rg*16 .. rg*16+15
    float acc[16];
#pragma unroll
    for (int rr = 0; rr < 16; ++rr) acc[rr] = 0.f;

    for (int k4 = 0; k4 < 128; k4 += 4) {
        float w0 = Wl[(k4 + 0) * 128 + c];
        float w1 = Wl[(k4 + 1) * 128 + c];
        float w2 = Wl[(k4 + 2) * 128 + c];
        float w3 = Wl[(k4 + 3) * 128 + c];
#pragma unroll
        for (int rr = 0; rr < 16; ++rr) {
            const float4 a = *((const float4*)&Al[(rg * 16 + rr) * 128 + k4]);
            acc[rr] = fmaf(a.x, w0, fmaf(a.y, w1, fmaf(a.z, w2, fmaf(a.w, w3, acc[rr]))));
        }
    }

#pragma unroll
    for (int rr = 0; rr < 16; ++rr) {
        int r = row0 + rg * 16 + rr;
        if (r < n) {
            size_t off = (size_t)r * 128 + c;
            float v = acc[rr];
            v = v > 0.f ? v : 0.f;
            v = v + R[off];
            O[off] = v;
            if (WRITE_BF16) {
                hb[off] = f2bf(v * invs[r]);
            }
        }
    }
}

// ---------------- seed gather ----------------
__global__ void gather_seeds(const int* __restrict__ seeds, const float* __restrict__ ent,
                             float* __restrict__ out, int S) {
    int idx = blockIdx.x * 256 + threadIdx.x;
    if (idx < S * 32) {
        int i = idx >> 5;
        int t = idx & 31;
        int s = seeds[i];
        ((float4*)out)[(size_t)i * 32 + t] = ((const float4*)ent)[(size_t)s * 32 + t];
    }
}

// ---------------- per-graph driver ----------------
static void run_graph(const int* edges, const float* emb, const float* W0, const float* W1,
                      float* ent_out, u32* hb, u32* aggb, float* invs, int* cnt_cursor,
                      int* rowptr, int* bsums, int* colb, int N, int E, hipStream_t stream) {
    hipMemsetAsync(cnt_cursor, 0, (size_t)N * 4, stream);
    int eb = (E + 255) / 256;
    int nb = (N + 255) / 256;
    count_edges<<<eb, 256, 0, stream>>>(edges, E, cnt_cursor);
    compute_invsqrt<<<nb, 256, 0, stream>>>(cnt_cursor, invs, N);
    scan_block<<<nb, 256, 0, stream>>>(cnt_cursor, rowptr, bsums, N);
    scan_bsums<<<1, 512, 0, stream>>>(bsums, nb);
    // add_offsets overlays the cursor into the (no-longer-needed) cnt buffer
    add_offsets<<<nb, 256, 0, stream>>>(rowptr, cnt_cursor, bsums, N, 2 * E);
    fill_csr<<<eb, 256, 0, stream>>>(edges, E, cnt_cursor, colb);

    int cb = (N * 64 + 255) / 256;
    int pb = (N + 3) / 4;  // 4 waves (nodes) per 256-thread block
    int gb = (N + 31) / 32;
    size_t shbytes = (128 * 128 + 32 * 128) * sizeof(float);  // 80KB

    // hb = bf16(emb * invs)
    cast_scale_bf16<<<cb, 256, 0, stream>>>(emb, invs, hb, N * 64);
    // layer 1
    pull_agg<<<pb, 256, 0, stream>>>(emb, hb, rowptr, colb, invs, aggb, N);
    gemm_relu_res<1><<<gb, 256, shbytes, stream>>>(aggb, W0, emb, invs, ent_out, (u16*)hb, N);
    // layer 2
    pull_agg<<<pb, 256, 0, stream>>>(ent_out, hb, rowptr, colb, invs, aggb, N);
    gemm_relu_res<0><<<gb, 256, shbytes, stream>>>(aggb, W1, ent_out, invs, ent_out, nullptr, N);
}

extern "C" void kernel_launch(void* const* d_in, const int* in_sizes, int n_in,
                              void* d_out, int out_size, void* d_ws, size_t ws_size,
                              hipStream_t stream) {
    const int* seeds_sr = (const int*)d_in[0];
    const int* seeds_tg = (const int*)d_in[1];
    const int* edges_sr = (const int*)d_in[2];
    const int* edges_tg = (const int*)d_in[3];
    const float* emb_sr = (const float*)d_in[4];
    const float* emb_tg = (const float*)d_in[5];
    const float* W0 = (const float*)d_in[6];
    const float* W1 = (const float*)d_in[7];

    int S = in_sizes[0];
    int E = in_sizes[2] / 2;
    int N = in_sizes[4] / D;

    float* out = (float*)d_out;
    float* out_sr_seed = out;
    float* out_tg_seed = out + (size_t)S * D;
    float* out_sr_ent = out + 2 * (size_t)S * D;
    float* out_tg_ent = out_sr_ent + (size_t)N * D;

    // workspace carve-up (all 256B aligned)
    char* w = (char*)d_ws;
    u32* hb = (u32*)w;        w += (size_t)N * 64 * 4;   // 25.6MB bf16 gather source
    u32* aggb = (u32*)w;      w += (size_t)N * 64 * 4;   // 25.6MB bf16 aggregate
    float* invs = (float*)w;  w += (size_t)N * 4;
    int* cnt_cursor = (int*)w; w += (size_t)N * 4;
    int* rowptr = (int*)w;    w += (size_t)(N + 64) * 4;
    int* bsums = (int*)w;     w += 4096;
    int* colb = (int*)w;      // 2*E ints = 12.8MB

    run_graph(edges_sr, emb_sr, W0, W1, out_sr_ent, hb, aggb, invs, cnt_cursor, rowptr, bsums,
              colb, N, E, stream);
    run_graph(edges_tg, emb_tg, W0, W1, out_tg_ent, hb, aggb, invs, cnt_cursor, rowptr, bsums,
              colb, N, E, stream);

    int sb = (S * 32 + 255) / 256;
    gather_seeds<<<sb, 256, 0, stream>>>(seeds_sr, out_sr_ent, out_sr_seed, S);
    gather_seeds<<<sb, 256, 0, stream>>>(seeds_tg, out_tg_ent, out_tg_seed, S);
}

// Round 4
// 1952.006 us; speedup vs baseline: 1.5006x; 1.1372x over previous
//
#include <hip/hip_runtime.h>

#define D 128
#define CAP 1600  // per-(xcd,bucket) pair capacity; mean occupancy ~1023, ~18 sigma slack

typedef unsigned int u32;
typedef unsigned short u16;

__device__ __forceinline__ float bflo(u32 u) { return __uint_as_float(u << 16); }
__device__ __forceinline__ float bfhi(u32 u) { return __uint_as_float(u & 0xffff0000u); }
__device__ __forceinline__ u16 f2bf(float x) {
    u32 u = __float_as_uint(x);
    u = (u + 0x7fffu + ((u >> 16) & 1u)) >> 16;  // round-to-nearest-even
    return (u16)u;
}
__device__ __forceinline__ u32 pack2bf(float a, float b) {
    return (u32)f2bf(a) | ((u32)f2bf(b) << 16);
}

__device__ __forceinline__ int xcd_id() {
    unsigned x;
    asm volatile("s_getreg_b32 %0, hwreg(HW_REG_XCC_ID)" : "=s"(x));
    return (int)(x & 7u);
}

// ---------------- scatter edges into per-(xcd,bucket) pair lists ----------------
// entry = (dst_local8 << 24) | src  (src < 2^17)
__global__ __launch_bounds__(256) void scatter_pairs(const int* __restrict__ e, int E,
                                                     int* __restrict__ cur,
                                                     u32* __restrict__ pairs, int NB,
                                                     int NB_PAD) {
    int i = blockIdx.x * 256 + threadIdx.x;
    if (i >= E) return;
    int xcd = xcd_id();
    int u = e[i];
    int v = e[E + i];
    {
        int b = v >> 8;
        int pos = atomicAdd(&cur[xcd * NB_PAD + b], 1);
        if (pos < CAP)
            pairs[((size_t)(xcd * NB + b)) * CAP + pos] = ((u32)(v & 255) << 24) | (u32)u;
    }
    {
        int b = u >> 8;
        int pos = atomicAdd(&cur[xcd * NB_PAD + b], 1);
        if (pos < CAP)
            pairs[((size_t)(xcd * NB + b)) * CAP + pos] = ((u32)(u & 255) << 24) | (u32)v;
    }
}

// ---------------- per-bucket totals -> exclusive scan -> col base ----------------
__global__ void bucket_scan(const int* __restrict__ cur, int* __restrict__ bucket_base,
                            int* __restrict__ rowptr, int NB, int NB_PAD, int N) {
    __shared__ int sm[512];
    int t = threadIdx.x;
    int v = 0;
    if (t < NB) {
        for (int x = 0; x < 8; ++x) {
            int c = cur[x * NB_PAD + t];
            v += (c < CAP) ? c : CAP;
        }
    }
    sm[t] = v;
    __syncthreads();
    for (int off = 1; off < 512; off <<= 1) {
        int x = (t >= off) ? sm[t - off] : 0;
        __syncthreads();
        sm[t] += x;
        __syncthreads();
    }
    if (t < NB) bucket_base[t] = sm[t] - v;  // exclusive
    if (t == 511) rowptr[N] = sm[511];       // total entries
}

// ---------------- finalize: one block per 256-node bucket ----------------
// LDS hist -> scan -> rowptr/invs, then scatter col within an L2-local region.
__global__ __launch_bounds__(256) void finalize_bucket(const u32* __restrict__ pairs,
                                                       const int* __restrict__ cur,
                                                       const int* __restrict__ bucket_base,
                                                       int* __restrict__ rowptr,
                                                       float* __restrict__ invs,
                                                       int* __restrict__ col, int N, int NB,
                                                       int NB_PAD) {
    __shared__ int lcnt[256];
    __shared__ int lofs[256];
    int b = blockIdx.x;
    int tid = threadIdx.x;
    int lo = b << 8;
    lcnt[tid] = 0;
    __syncthreads();
    // A: histogram over node-locals
    for (int x = 0; x < 8; ++x) {
        int n = cur[x * NB_PAD + b];
        n = (n < CAP) ? n : CAP;
        const u32* p = pairs + ((size_t)(x * NB + b)) * CAP;
        for (int k = tid; k < n; k += 256) atomicAdd(&lcnt[p[k] >> 24], 1);
    }
    __syncthreads();
    // B: inclusive scan -> exclusive offsets
    int v = lcnt[tid];
    lofs[tid] = v;
    __syncthreads();
    for (int off = 1; off < 256; off <<= 1) {
        int t2 = (tid >= off) ? lofs[tid - off] : 0;
        __syncthreads();
        lofs[tid] += t2;
        __syncthreads();
    }
    int mystart = bucket_base[b] + lofs[tid] - v;
    int node = lo + tid;
    if (node < N) {
        rowptr[node] = mystart;
        invs[node] = rsqrtf((float)(v + 1));  // +1 self loop
    }
    lofs[tid] = mystart;  // reuse as per-node cursor
    __syncthreads();
    // C: scatter col (region is small + one-XCD-local -> L2 write combining)
    for (int x = 0; x < 8; ++x) {
        int n = cur[x * NB_PAD + b];
        n = (n < CAP) ? n : CAP;
        const u32* p = pairs + ((size_t)(x * NB + b)) * CAP;
        for (int k = tid; k < n; k += 256) {
            u32 w = p[k];
            int pos = atomicAdd(&lofs[w >> 24], 1);
            col[pos] = (int)(w & 0x00FFFFFFu);
        }
    }
}

// ---------------- cast + pre-scale: hb[i] = bf16(h[i] * invs[row]) ----------------
__global__ void cast_scale_bf16(const float* __restrict__ h, const float* __restrict__ invs,
                                u32* __restrict__ hb, int n64) {
    int idx = blockIdx.x * 256 + threadIdx.x;
    if (idx >= n64) return;
    int row = idx >> 6;
    float is = invs[row];
    float2 v = ((const float2*)h)[idx];
    hb[idx] = pack2bf(v.x * is, v.y * is);
}

// ---------------- pull aggregation: one wave per node, bf16 pre-scaled gather --------
__global__ __launch_bounds__(256) void pull_agg(const float* __restrict__ hself,
                                                const u32* __restrict__ hb,
                                                const int* __restrict__ rowptr,
                                                const int* __restrict__ col,
                                                const float* __restrict__ invs,
                                                u32* __restrict__ aggb, int n) {
    int gw = (blockIdx.x * 256 + threadIdx.x) >> 6;  // global wave id = node
    if (gw >= n) return;
    int lane = threadIdx.x & 63;
    float inv_n = invs[gw];
    size_t rowbase = (size_t)gw * 64;
    float2 hv = ((const float2*)hself)[rowbase + lane];
    float ax = hv.x * inv_n;
    float ay = hv.y * inv_n;
    int j = rowptr[gw];
    int end = rowptr[gw + 1];
    for (; j + 4 <= end; j += 4) {
        int s0 = col[j], s1 = col[j + 1], s2 = col[j + 2], s3 = col[j + 3];
        u32 u0 = hb[(size_t)s0 * 64 + lane];
        u32 u1 = hb[(size_t)s1 * 64 + lane];
        u32 u2 = hb[(size_t)s2 * 64 + lane];
        u32 u3 = hb[(size_t)s3 * 64 + lane];
        ax += (bflo(u0) + bflo(u1)) + (bflo(u2) + bflo(u3));
        ay += (bfhi(u0) + bfhi(u1)) + (bfhi(u2) + bfhi(u3));
    }
    for (; j < end; ++j) {
        int s = col[j];
        u32 u = hb[(size_t)s * 64 + lane];
        ax += bflo(u);
        ay += bfhi(u);
    }
    aggb[rowbase + lane] = pack2bf(ax * inv_n, ay * inv_n);
}

// ---------------- fused  O = relu(unpack(Ab) @ W) + R, optional bf16 writeback -------
template <int WRITE_BF16>
__global__ __launch_bounds__(256) void gemm_relu_res(const u32* __restrict__ Ab,
                                                     const float* __restrict__ W,
                                                     const float* __restrict__ R,
                                                     const float* __restrict__ invs,
                                                     float* __restrict__ O,
                                                     u16* __restrict__ hb, int n) {
    extern __shared__ float smem[];
    float* Wl = smem;              // 128*128 fp32
    float* Al = smem + 128 * 128;  // 32*128 fp32
    int tid = threadIdx.x;
    for (int idx = tid; idx < 4096; idx += 256) {
        ((float4*)Wl)[idx] = ((const float4*)W)[idx];
    }
    int row0 = blockIdx.x * 32;
    for (int idx = tid; idx < 2048; idx += 256) {
        int r = idx >> 6;
        int p = idx & 63;
        u32 u = (row0 + r < n) ? Ab[(size_t)(row0 + r) * 64 + p] : 0u;
        Al[r * 128 + 2 * p] = bflo(u);
        Al[r * 128 + 2 * p + 1] = bfhi(u);
    }
    __syncthreads();

    int c = tid & 127;
    int rg = tid >> 7;
    float acc[16];
#pragma unroll
    for (int rr = 0; rr < 16; ++rr) acc[rr] = 0.f;

    for (int k4 = 0; k4 < 128; k4 += 4) {
        float w0 = Wl[(k4 + 0) * 128 + c];
        float w1 = Wl[(k4 + 1) * 128 + c];
        float w2 = Wl[(k4 + 2) * 128 + c];
        float w3 = Wl[(k4 + 3) * 128 + c];
#pragma unroll
        for (int rr = 0; rr < 16; ++rr) {
            const float4 a = *((const float4*)&Al[(rg * 16 + rr) * 128 + k4]);
            acc[rr] = fmaf(a.x, w0, fmaf(a.y, w1, fmaf(a.z, w2, fmaf(a.w, w3, acc[rr]))));
        }
    }

#pragma unroll
    for (int rr = 0; rr < 16; ++rr) {
        int r = row0 + rg * 16 + rr;
        if (r < n) {
            size_t off = (size_t)r * 128 + c;
            float v = acc[rr];
            v = v > 0.f ? v : 0.f;
            v = v + R[off];
            O[off] = v;
            if (WRITE_BF16) {
                hb[off] = f2bf(v * invs[r]);
            }
        }
    }
}

// ---------------- seed gather ----------------
__global__ void gather_seeds(const int* __restrict__ seeds, const float* __restrict__ ent,
                             float* __restrict__ out, int S) {
    int idx = blockIdx.x * 256 + threadIdx.x;
    if (idx < S * 32) {
        int i = idx >> 5;
        int t = idx & 31;
        int s = seeds[i];
        ((float4*)out)[(size_t)i * 32 + t] = ((const float4*)ent)[(size_t)s * 32 + t];
    }
}

// ---------------- per-graph driver ----------------
static void run_graph(const int* edges, const float* emb, const float* W0, const float* W1,
                      float* ent_out, u32* hb, u32* aggb, u32* pairs, float* invs,
                      int* rowptr, int* colb, int* cur, int* bucket_base, int N, int E,
                      int NB, int NB_PAD, hipStream_t stream) {
    hipMemsetAsync(cur, 0, (size_t)8 * NB_PAD * 4, stream);
    int eb = (E + 255) / 256;
    scatter_pairs<<<eb, 256, 0, stream>>>(edges, E, cur, pairs, NB, NB_PAD);
    bucket_scan<<<1, 512, 0, stream>>>(cur, bucket_base, rowptr, NB, NB_PAD, N);
    finalize_bucket<<<NB, 256, 0, stream>>>(pairs, cur, bucket_base, rowptr, invs, colb, N,
                                            NB, NB_PAD);

    int cb = (N * 64 + 255) / 256;
    int pb = (N + 3) / 4;
    int gb = (N + 31) / 32;
    size_t shbytes = (128 * 128 + 32 * 128) * sizeof(float);  // 80KB

    cast_scale_bf16<<<cb, 256, 0, stream>>>(emb, invs, hb, N * 64);
    pull_agg<<<pb, 256, 0, stream>>>(emb, hb, rowptr, colb, invs, aggb, N);
    gemm_relu_res<1><<<gb, 256, shbytes, stream>>>(aggb, W0, emb, invs, ent_out, (u16*)hb, N);
    pull_agg<<<pb, 256, 0, stream>>>(ent_out, hb, rowptr, colb, invs, aggb, N);
    gemm_relu_res<0><<<gb, 256, shbytes, stream>>>(aggb, W1, ent_out, invs, ent_out, nullptr, N);
}

extern "C" void kernel_launch(void* const* d_in, const int* in_sizes, int n_in,
                              void* d_out, int out_size, void* d_ws, size_t ws_size,
                              hipStream_t stream) {
    const int* seeds_sr = (const int*)d_in[0];
    const int* seeds_tg = (const int*)d_in[1];
    const int* edges_sr = (const int*)d_in[2];
    const int* edges_tg = (const int*)d_in[3];
    const float* emb_sr = (const float*)d_in[4];
    const float* emb_tg = (const float*)d_in[5];
    const float* W0 = (const float*)d_in[6];
    const float* W1 = (const float*)d_in[7];

    int S = in_sizes[0];
    int E = in_sizes[2] / 2;
    int N = in_sizes[4] / D;
    int NB = (N + 255) / 256;
    int NB_PAD = (NB + 15) & ~15;  // per-XCD cursor slice is 64B-line-disjoint

    float* out = (float*)d_out;
    float* out_sr_seed = out;
    float* out_tg_seed = out + (size_t)S * D;
    float* out_sr_ent = out + 2 * (size_t)S * D;
    float* out_tg_ent = out_sr_ent + (size_t)N * D;

    // workspace carve-up
    char* w = (char*)d_ws;
    u32* hb = (u32*)w;         w += (size_t)N * 64 * 4;  // 25.6MB bf16 gather source
    u32* aggb = (u32*)w;       w += (size_t)N * 64 * 4;  // 25.6MB bf16 aggregate
    u32* pairs = aggb;         // ALIAS: pairs (20MB) dead before aggb first written
    float* invs = (float*)w;   w += (size_t)N * 4;
    int* rowptr = (int*)w;     w += (size_t)(N + 64) * 4;
    int* colb = (int*)w;       w += (size_t)2 * E * 4;   // 12.8MB
    int* cur = (int*)w;        w += (size_t)8 * NB_PAD * 4;
    int* bucket_base = (int*)w;

    run_graph(edges_sr, emb_sr, W0, W1, out_sr_ent, hb, aggb, pairs, invs, rowptr, colb, cur,
              bucket_base, N, E, NB, NB_PAD, stream);
    run_graph(edges_tg, emb_tg, W0, W1, out_tg_ent, hb, aggb, pairs, invs, rowptr, colb, cur,
              bucket_base, N, E, NB, NB_PAD, stream);

    int sb = (S * 32 + 255) / 256;
    gather_seeds<<<sb, 256, 0, stream>>>(seeds_sr, out_sr_ent, out_sr_seed, S);
    gather_seeds<<<sb, 256, 0, stream>>>(seeds_tg, out_tg_ent, out_tg_seed, S);
}

// Round 5
// 1508.942 us; speedup vs baseline: 1.9413x; 1.2936x over previous
//
#include <hip/hip_runtime.h>

#define D 128
#define NWG 256  // workgroups for the two edge passes (1 per CU)

typedef unsigned int u32;
typedef unsigned short u16;

__device__ __forceinline__ float bflo(u32 u) { return __uint_as_float(u << 16); }
__device__ __forceinline__ float bfhi(u32 u) { return __uint_as_float(u & 0xffff0000u); }
__device__ __forceinline__ u16 f2bf(float x) {
    u32 u = __float_as_uint(x);
    u = (u + 0x7fffu + ((u >> 16) & 1u)) >> 16;  // round-to-nearest-even
    return (u16)u;
}
__device__ __forceinline__ u32 pack2bf(float a, float b) {
    return (u32)f2bf(a) | ((u32)f2bf(b) << 16);
}

// ---------------- pass 1: per-(bucket, block) histogram via LDS atomics ----------------
__global__ __launch_bounds__(256) void pass1_hist(const int* __restrict__ e, int E, int chunk,
                                                  int* __restrict__ hist, int NB) {
    __shared__ int lcnt[512];
    int w = blockIdx.x, tid = threadIdx.x;
    for (int b = tid; b < NB; b += 256) lcnt[b] = 0;
    __syncthreads();
    int beg = w * chunk;
    int end = min(E, beg + chunk);
    if (beg < end) {
        int n4 = (end - beg) >> 2;
        for (int g = tid; g < n4; g += 256) {
            int i = beg + g * 4;
            int4 us = *(const int4*)(e + i);
            int4 vs = *(const int4*)(e + E + i);
            atomicAdd(&lcnt[us.x >> 8], 1);
            atomicAdd(&lcnt[vs.x >> 8], 1);
            atomicAdd(&lcnt[us.y >> 8], 1);
            atomicAdd(&lcnt[vs.y >> 8], 1);
            atomicAdd(&lcnt[us.z >> 8], 1);
            atomicAdd(&lcnt[vs.z >> 8], 1);
            atomicAdd(&lcnt[us.w >> 8], 1);
            atomicAdd(&lcnt[vs.w >> 8], 1);
        }
        for (int i = beg + n4 * 4 + tid; i < end; i += 256) {
            atomicAdd(&lcnt[e[i] >> 8], 1);
            atomicAdd(&lcnt[e[E + i] >> 8], 1);
        }
    }
    __syncthreads();
    for (int b = tid; b < NB; b += 256) hist[b * NWG + w] = lcnt[b];
}

// ---------------- exclusive scan (2-level), reused ----------------
__global__ void scan_block(const int* __restrict__ cnt, int* __restrict__ excl,
                           int* __restrict__ bsums, int n) {
    __shared__ int sm[256];
    int i = blockIdx.x * 256 + threadIdx.x;
    int v = (i < n) ? cnt[i] : 0;
    sm[threadIdx.x] = v;
    __syncthreads();
    for (int off = 1; off < 256; off <<= 1) {
        int t = (threadIdx.x >= off) ? sm[threadIdx.x - off] : 0;
        __syncthreads();
        sm[threadIdx.x] += t;
        __syncthreads();
    }
    if (i < n) excl[i] = sm[threadIdx.x] - v;
    if (threadIdx.x == 255) bsums[blockIdx.x] = sm[255];
}

__global__ void scan_bsums(int* __restrict__ bsums, int nb) {
    __shared__ int sm[512];
    int t = threadIdx.x;
    int v = (t < nb) ? bsums[t] : 0;
    sm[t] = v;
    __syncthreads();
    for (int off = 1; off < 512; off <<= 1) {
        int x = (t >= off) ? sm[t - off] : 0;
        __syncthreads();
        sm[t] += x;
        __syncthreads();
    }
    if (t < nb) bsums[t] = sm[t] - v;  // exclusive
}

__global__ void add_offsets2(int* __restrict__ data, const int* __restrict__ bsums, int n) {
    int i = blockIdx.x * 256 + threadIdx.x;
    if (i < n) data[i] += bsums[blockIdx.x];
}

// ---------------- pass 2: deterministic scatter via LDS bump cursors ----------------
__global__ __launch_bounds__(256) void pass2_scatter(const int* __restrict__ e, int E,
                                                     int chunk, const int* __restrict__ hsc,
                                                     u32* __restrict__ pairs, int NB) {
    __shared__ int lbase[512];
    int w = blockIdx.x, tid = threadIdx.x;
    for (int b = tid; b < NB; b += 256) lbase[b] = hsc[b * NWG + w];
    __syncthreads();
    int beg = w * chunk;
    int end = min(E, beg + chunk);
    if (beg >= end) return;
    auto emit = [&](int dstn, int srcn) {
        int b = dstn >> 8;
        int pos = atomicAdd(&lbase[b], 1);
        pairs[pos] = ((u32)(dstn & 255) << 24) | (u32)srcn;
    };
    int n4 = (end - beg) >> 2;
    for (int g = tid; g < n4; g += 256) {
        int i = beg + g * 4;
        int4 us = *(const int4*)(e + i);
        int4 vs = *(const int4*)(e + E + i);
        emit(us.x, vs.x); emit(vs.x, us.x);
        emit(us.y, vs.y); emit(vs.y, us.y);
        emit(us.z, vs.z); emit(vs.z, us.z);
        emit(us.w, vs.w); emit(vs.w, us.w);
    }
    for (int i = beg + n4 * 4 + tid; i < end; i += 256) {
        int u = e[i], v = e[E + i];
        emit(v, u);
        emit(u, v);
    }
}

// ---------------- finalize: one block per 256-node bucket (contiguous range) ----------
__global__ __launch_bounds__(256) void finalize_bucket(const u32* __restrict__ pairs,
                                                       const int* __restrict__ hsc,
                                                       int* __restrict__ rowptr,
                                                       float* __restrict__ invs,
                                                       int* __restrict__ col, int N, int NB,
                                                       int total) {
    __shared__ int lcnt[256];
    __shared__ int lofs[256];
    int b = blockIdx.x, tid = threadIdx.x;
    int start = hsc[b * NWG];
    int end = (b + 1 < NB) ? hsc[(b + 1) * NWG] : total;
    lcnt[tid] = 0;
    __syncthreads();
    for (int k = start + tid; k < end; k += 256) atomicAdd(&lcnt[pairs[k] >> 24], 1);
    __syncthreads();
    int v = lcnt[tid];
    lofs[tid] = v;
    __syncthreads();
    for (int off = 1; off < 256; off <<= 1) {
        int t2 = (tid >= off) ? lofs[tid - off] : 0;
        __syncthreads();
        lofs[tid] += t2;
        __syncthreads();
    }
    int mystart = start + lofs[tid] - v;
    int node = (b << 8) + tid;
    if (node < N) {
        rowptr[node] = mystart;
        invs[node] = rsqrtf((float)(v + 1));  // +1 self loop
    }
    if (b == NB - 1 && tid == 0) rowptr[N] = total;
    lofs[tid] = mystart;  // reuse as per-node cursor
    __syncthreads();
    for (int k = start + tid; k < end; k += 256) {
        u32 wv = pairs[k];
        int pos = atomicAdd(&lofs[wv >> 24], 1);
        col[pos] = (int)(wv & 0x00FFFFFFu);
    }
}

// ---------------- cast + pre-scale: hb[i] = bf16(h[i] * invs[row]) ----------------
__global__ void cast_scale_bf16(const float* __restrict__ h, const float* __restrict__ invs,
                                u32* __restrict__ hb, int n64) {
    int idx = blockIdx.x * 256 + threadIdx.x;
    if (idx >= n64) return;
    int row = idx >> 6;
    float is = invs[row];
    float2 v = ((const float2*)h)[idx];
    hb[idx] = pack2bf(v.x * is, v.y * is);
}

// ---------------- pull aggregation: one wave per node, bf16 pre-scaled gather --------
__global__ __launch_bounds__(256) void pull_agg(const float* __restrict__ hself,
                                                const u32* __restrict__ hb,
                                                const int* __restrict__ rowptr,
                                                const int* __restrict__ col,
                                                const float* __restrict__ invs,
                                                u32* __restrict__ aggb, int n) {
    int gw = (blockIdx.x * 256 + threadIdx.x) >> 6;  // global wave id = node
    if (gw >= n) return;
    int lane = threadIdx.x & 63;
    float inv_n = invs[gw];
    size_t rowbase = (size_t)gw * 64;
    float2 hv = ((const float2*)hself)[rowbase + lane];
    float ax = hv.x * inv_n;
    float ay = hv.y * inv_n;
    int j = rowptr[gw];
    int end = rowptr[gw + 1];
    for (; j + 4 <= end; j += 4) {
        int s0 = col[j], s1 = col[j + 1], s2 = col[j + 2], s3 = col[j + 3];
        u32 u0 = hb[(size_t)s0 * 64 + lane];
        u32 u1 = hb[(size_t)s1 * 64 + lane];
        u32 u2 = hb[(size_t)s2 * 64 + lane];
        u32 u3 = hb[(size_t)s3 * 64 + lane];
        ax += (bflo(u0) + bflo(u1)) + (bflo(u2) + bflo(u3));
        ay += (bfhi(u0) + bfhi(u1)) + (bfhi(u2) + bfhi(u3));
    }
    for (; j < end; ++j) {
        int s = col[j];
        u32 u = hb[(size_t)s * 64 + lane];
        ax += bflo(u);
        ay += bfhi(u);
    }
    aggb[rowbase + lane] = pack2bf(ax * inv_n, ay * inv_n);
}

// ---------------- fused  O = relu(unpack(Ab) @ W) + R, optional bf16 writeback -------
template <int WRITE_BF16>
__global__ __launch_bounds__(256) void gemm_relu_res(const u32* __restrict__ Ab,
                                                     const float* __restrict__ W,
                                                     const float* __restrict__ R,
                                                     const float* __restrict__ invs,
                                                     float* __restrict__ O,
                                                     u16* __restrict__ hb, int n) {
    extern __shared__ float smem[];
    float* Wl = smem;              // 128*128 fp32
    float* Al = smem + 128 * 128;  // 32*128 fp32
    int tid = threadIdx.x;
    for (int idx = tid; idx < 4096; idx += 256) {
        ((float4*)Wl)[idx] = ((const float4*)W)[idx];
    }
    int row0 = blockIdx.x * 32;
    for (int idx = tid; idx < 2048; idx += 256) {
        int r = idx >> 6;
        int p = idx & 63;
        u32 u = (row0 + r < n) ? Ab[(size_t)(row0 + r) * 64 + p] : 0u;
        Al[r * 128 + 2 * p] = bflo(u);
        Al[r * 128 + 2 * p + 1] = bfhi(u);
    }
    __syncthreads();

    int c = tid & 127;
    int rg = tid >> 7;
    float acc[16];
#pragma unroll
    for (int rr = 0; rr < 16; ++rr) acc[rr] = 0.f;

    for (int k4 = 0; k4 < 128; k4 += 4) {
        float w0 = Wl[(k4 + 0) * 128 + c];
        float w1 = Wl[(k4 + 1) * 128 + c];
        float w2 = Wl[(k4 + 2) * 128 + c];
        float w3 = Wl[(k4 + 3) * 128 + c];
#pragma unroll
        for (int rr = 0; rr < 16; ++rr) {
            const float4 a = *((const float4*)&Al[(rg * 16 + rr) * 128 + k4]);
            acc[rr] = fmaf(a.x, w0, fmaf(a.y, w1, fmaf(a.z, w2, fmaf(a.w, w3, acc[rr]))));
        }
    }

#pragma unroll
    for (int rr = 0; rr < 16; ++rr) {
        int r = row0 + rg * 16 + rr;
        if (r < n) {
            size_t off = (size_t)r * 128 + c;
            float v = acc[rr];
            v = v > 0.f ? v : 0.f;
            v = v + R[off];
            O[off] = v;
            if (WRITE_BF16) {
                hb[off] = f2bf(v * invs[r]);
            }
        }
    }
}

// ---------------- seed gather ----------------
__global__ void gather_seeds(const int* __restrict__ seeds, const float* __restrict__ ent,
                             float* __restrict__ out, int S) {
    int idx = blockIdx.x * 256 + threadIdx.x;
    if (idx < S * 32) {
        int i = idx >> 5;
        int t = idx & 31;
        int s = seeds[i];
        ((float4*)out)[(size_t)i * 32 + t] = ((const float4*)ent)[(size_t)s * 32 + t];
    }
}

// ---------------- per-graph driver ----------------
static void run_graph(const int* edges, const float* emb, const float* W0, const float* W1,
                      float* ent_out, u32* hb, u32* aggb, int* hist, u32* pairs, int* hsc,
                      float* invs, int* rowptr, int* colb, int* bsums, int N, int E, int NB,
                      hipStream_t stream) {
    int chunk = (((E + NWG - 1) / NWG) + 3) & ~3;  // 4-aligned per-block edge chunk
    int M = NB * NWG;                              // histogram matrix size
    int sblk = (M + 255) / 256;                    // == NB when NWG==256

    pass1_hist<<<NWG, 256, 0, stream>>>(edges, E, chunk, hist, NB);
    scan_block<<<sblk, 256, 0, stream>>>(hist, hsc, bsums, M);
    scan_bsums<<<1, 512, 0, stream>>>(bsums, sblk);
    add_offsets2<<<sblk, 256, 0, stream>>>(hsc, bsums, M);
    pass2_scatter<<<NWG, 256, 0, stream>>>(edges, E, chunk, hsc, pairs, NB);
    finalize_bucket<<<NB, 256, 0, stream>>>(pairs, hsc, rowptr, invs, colb, N, NB, 2 * E);

    int cb = (N * 64 + 255) / 256;
    int pb = (N + 3) / 4;
    int gb = (N + 31) / 32;
    size_t shbytes = (128 * 128 + 32 * 128) * sizeof(float);  // 80KB

    cast_scale_bf16<<<cb, 256, 0, stream>>>(emb, invs, hb, N * 64);
    pull_agg<<<pb, 256, 0, stream>>>(emb, hb, rowptr, colb, invs, aggb, N);
    gemm_relu_res<1><<<gb, 256, shbytes, stream>>>(aggb, W0, emb, invs, ent_out, (u16*)hb, N);
    pull_agg<<<pb, 256, 0, stream>>>(ent_out, hb, rowptr, colb, invs, aggb, N);
    gemm_relu_res<0><<<gb, 256, shbytes, stream>>>(aggb, W1, ent_out, invs, ent_out, nullptr, N);
}

extern "C" void kernel_launch(void* const* d_in, const int* in_sizes, int n_in,
                              void* d_out, int out_size, void* d_ws, size_t ws_size,
                              hipStream_t stream) {
    const int* seeds_sr = (const int*)d_in[0];
    const int* seeds_tg = (const int*)d_in[1];
    const int* edges_sr = (const int*)d_in[2];
    const int* edges_tg = (const int*)d_in[3];
    const float* emb_sr = (const float*)d_in[4];
    const float* emb_tg = (const float*)d_in[5];
    const float* W0 = (const float*)d_in[6];
    const float* W1 = (const float*)d_in[7];

    int S = in_sizes[0];
    int E = in_sizes[2] / 2;
    int N = in_sizes[4] / D;
    int NB = (N + 255) / 256;

    float* out = (float*)d_out;
    float* out_sr_seed = out;
    float* out_tg_seed = out + (size_t)S * D;
    float* out_sr_ent = out + 2 * (size_t)S * D;
    float* out_tg_ent = out_sr_ent + (size_t)N * D;

    // workspace carve-up (aliases commented with lifetime proofs)
    char* w = (char*)d_ws;
    u32* hb = (u32*)w;   w += (size_t)N * 64 * 4;  // 25.6MB bf16 gather source
    u32* aggb = (u32*)w; w += (size_t)N * 64 * 4;  // 25.6MB bf16 aggregate
    // hist aliases hb: hist dead after scan_block; hb first written by cast_scale (later)
    int* hist = (int*)hb;
    // pairs + hsc alias aggb (disjoint offsets): both dead before pull_agg writes aggb
    u32* pairs = aggb;                     // 2E*4 = 12.8MB < 16MB
    int* hsc = (int*)(aggb + (1 << 22));   // +16MB; NB*NWG*4 ≈ 0.4MB
    float* invs = (float*)w;  w += (size_t)N * 4;
    int* rowptr = (int*)w;    w += (size_t)(N + 64) * 4;
    int* colb = (int*)w;      w += (size_t)2 * E * 4;  // 12.8MB
    int* bsums = (int*)w;     // ≤512 ints used

    run_graph(edges_sr, emb_sr, W0, W1, out_sr_ent, hb, aggb, hist, pairs, hsc, invs, rowptr,
              colb, bsums, N, E, NB, stream);
    run_graph(edges_tg, emb_tg, W0, W1, out_tg_ent, hb, aggb, hist, pairs, hsc, invs, rowptr,
              colb, bsums, N, E, NB, stream);

    int sb = (S * 32 + 255) / 256;
    gather_seeds<<<sb, 256, 0, stream>>>(seeds_sr, out_sr_ent, out_sr_seed, S);
    gather_seeds<<<sb, 256, 0, stream>>>(seeds_tg, out_tg_ent, out_tg_seed, S);
}

// Round 10
// 977.616 us; speedup vs baseline: 2.9963x; 1.5435x over previous
//
#include <hip/hip_runtime.h>

#define D 128
#define NWG 256  // workgroups for the two edge passes

typedef unsigned int u32;
typedef unsigned short u16;
typedef __attribute__((ext_vector_type(8))) short bf16x8;
typedef __attribute__((ext_vector_type(4))) float f32x4;

__device__ __forceinline__ float bflo(u32 u) { return __uint_as_float(u << 16); }
__device__ __forceinline__ float bfhi(u32 u) { return __uint_as_float(u & 0xffff0000u); }
__device__ __forceinline__ u16 f2bf(float x) {
    u32 u = __float_as_uint(x);
    u = (u + 0x7fffu + ((u >> 16) & 1u)) >> 16;  // round-to-nearest-even
    return (u16)u;
}
__device__ __forceinline__ u32 pack2bf(float a, float b) {
    return (u32)f2bf(a) | ((u32)f2bf(b) << 16);
}

// ---------------- pass 1: per-(bucket, block) histogram via LDS atomics ----------------
__global__ __launch_bounds__(256) void pass1_hist(const int* __restrict__ e, int E, int chunk,
                                                  int* __restrict__ hist, int NB) {
    __shared__ int lcnt[512];
    int w = blockIdx.x, tid = threadIdx.x;
    for (int b = tid; b < NB; b += 256) lcnt[b] = 0;
    __syncthreads();
    int beg = w * chunk;
    int end = min(E, beg + chunk);
    if (beg < end) {
        int n4 = (end - beg) >> 2;
        for (int g = tid; g < n4; g += 256) {
            int i = beg + g * 4;
            int4 us = *(const int4*)(e + i);
            int4 vs = *(const int4*)(e + E + i);
            atomicAdd(&lcnt[us.x >> 8], 1);
            atomicAdd(&lcnt[vs.x >> 8], 1);
            atomicAdd(&lcnt[us.y >> 8], 1);
            atomicAdd(&lcnt[vs.y >> 8], 1);
            atomicAdd(&lcnt[us.z >> 8], 1);
            atomicAdd(&lcnt[vs.z >> 8], 1);
            atomicAdd(&lcnt[us.w >> 8], 1);
            atomicAdd(&lcnt[vs.w >> 8], 1);
        }
        for (int i = beg + n4 * 4 + tid; i < end; i += 256) {
            atomicAdd(&lcnt[e[i] >> 8], 1);
            atomicAdd(&lcnt[e[E + i] >> 8], 1);
        }
    }
    __syncthreads();
    for (int b = tid; b < NB; b += 256) hist[b * NWG + w] = lcnt[b];
}

// ---------------- exclusive scan (2-level) ----------------
__global__ void scan_block(const int* __restrict__ cnt, int* __restrict__ excl,
                           int* __restrict__ bsums, int n) {
    __shared__ int sm[256];
    int i = blockIdx.x * 256 + threadIdx.x;
    int v = (i < n) ? cnt[i] : 0;
    sm[threadIdx.x] = v;
    __syncthreads();
    for (int off = 1; off < 256; off <<= 1) {
        int t = (threadIdx.x >= off) ? sm[threadIdx.x - off] : 0;
        __syncthreads();
        sm[threadIdx.x] += t;
        __syncthreads();
    }
    if (i < n) excl[i] = sm[threadIdx.x] - v;
    if (threadIdx.x == 255) bsums[blockIdx.x] = sm[255];
}

__global__ void scan_bsums(int* __restrict__ bsums, int nb) {
    __shared__ int sm[512];
    int t = threadIdx.x;
    int v = (t < nb) ? bsums[t] : 0;
    sm[t] = v;
    __syncthreads();
    for (int off = 1; off < 512; off <<= 1) {
        int x = (t >= off) ? sm[t - off] : 0;
        __syncthreads();
        sm[t] += x;
        __syncthreads();
    }
    if (t < nb) bsums[t] = sm[t] - v;  // exclusive
}

__global__ void add_offsets2(int* __restrict__ data, const int* __restrict__ bsums, int n) {
    int i = blockIdx.x * 256 + threadIdx.x;
    if (i < n) data[i] += bsums[blockIdx.x];
}

// ---------------- pass 2: deterministic scatter via LDS bump cursors ----------------
__global__ __launch_bounds__(256) void pass2_scatter(const int* __restrict__ e, int E,
                                                     int chunk, const int* __restrict__ hsc,
                                                     u32* __restrict__ pairs, int NB) {
    __shared__ int lbase[512];
    int w = blockIdx.x, tid = threadIdx.x;
    for (int b = tid; b < NB; b += 256) lbase[b] = hsc[b * NWG + w];
    __syncthreads();
    int beg = w * chunk;
    int end = min(E, beg + chunk);
    if (beg >= end) return;
    auto emit = [&](int dstn, int srcn) {
        int b = dstn >> 8;
        int pos = atomicAdd(&lbase[b], 1);
        pairs[pos] = ((u32)(dstn & 255) << 24) | (u32)srcn;
    };
    int n4 = (end - beg) >> 2;
    for (int g = tid; g < n4; g += 256) {
        int i = beg + g * 4;
        int4 us = *(const int4*)(e + i);
        int4 vs = *(const int4*)(e + E + i);
        emit(us.x, vs.x); emit(vs.x, us.x);
        emit(us.y, vs.y); emit(vs.y, us.y);
        emit(us.z, vs.z); emit(vs.z, us.z);
        emit(us.w, vs.w); emit(vs.w, us.w);
    }
    for (int i = beg + n4 * 4 + tid; i < end; i += 256) {
        int u = e[i], v = e[E + i];
        emit(v, u);
        emit(u, v);
    }
}

// ---------------- finalize: one block per 256-node bucket (contiguous range) ----------
__global__ __launch_bounds__(256) void finalize_bucket(const u32* __restrict__ pairs,
                                                       const int* __restrict__ hsc,
                                                       int* __restrict__ rowptr,
                                                       float* __restrict__ invs,
                                                       int* __restrict__ col, int N, int NB,
                                                       int total) {
    __shared__ int lcnt[256];
    __shared__ int lofs[256];
    int b = blockIdx.x, tid = threadIdx.x;
    int start = hsc[b * NWG];
    int end = (b + 1 < NB) ? hsc[(b + 1) * NWG] : total;
    lcnt[tid] = 0;
    __syncthreads();
    for (int k = start + tid; k < end; k += 256) atomicAdd(&lcnt[pairs[k] >> 24], 1);
    __syncthreads();
    int v = lcnt[tid];
    lofs[tid] = v;
    __syncthreads();
    for (int off = 1; off < 256; off <<= 1) {
        int t2 = (tid >= off) ? lofs[tid - off] : 0;
        __syncthreads();
        lofs[tid] += t2;
        __syncthreads();
    }
    int mystart = start + lofs[tid] - v;
    int node = (b << 8) + tid;
    if (node < N) {
        rowptr[node] = mystart;
        invs[node] = rsqrtf((float)(v + 1));  // +1 self loop
    }
    if (b == NB - 1 && tid == 0) rowptr[N] = total;
    lofs[tid] = mystart;  // reuse as per-node cursor
    __syncthreads();
    for (int k = start + tid; k < end; k += 256) {
        u32 wv = pairs[k];
        int pos = atomicAdd(&lofs[wv >> 24], 1);
        col[pos] = (int)(wv & 0x00FFFFFFu);
    }
}

// ---------------- cast + pre-scale: hb[i] = bf16(h[i] * invs[row]) ----------------
__global__ void cast_scale_bf16(const float* __restrict__ h, const float* __restrict__ invs,
                                u32* __restrict__ hb, int n64) {
    int idx = blockIdx.x * 256 + threadIdx.x;
    if (idx >= n64) return;
    int row = idx >> 6;
    float is = invs[row];
    float2 v = ((const float2*)h)[idx];
    hb[idx] = pack2bf(v.x * is, v.y * is);
}

// ---------------- W -> bf16 transposed (Wt[c][k] = bf16(W[k][c])) ----------------
__global__ void transpose_cast_w(const float* __restrict__ W, u16* __restrict__ Wt) {
    int idx = blockIdx.x * 256 + threadIdx.x;  // 64 blocks x 256 = 16384
    int k = idx >> 7, c = idx & 127;
    Wt[c * 128 + k] = f2bf(W[idx]);
}

// ---------------- pull aggregation: one wave per node, bf16 pre-scaled gather --------
__global__ __launch_bounds__(256) void pull_agg(const float* __restrict__ hself,
                                                const u32* __restrict__ hb,
                                                const int* __restrict__ rowptr,
                                                const int* __restrict__ col,
                                                const float* __restrict__ invs,
                                                u32* __restrict__ aggb, int n) {
    int gw = (blockIdx.x * 256 + threadIdx.x) >> 6;  // global wave id = node
    if (gw >= n) return;
    int lane = threadIdx.x & 63;
    float inv_n = invs[gw];
    size_t rowbase = (size_t)gw * 64;
    float2 hv = ((const float2*)hself)[rowbase + lane];
    float ax = hv.x * inv_n;
    float ay = hv.y * inv_n;
    int j = rowptr[gw];
    int end = rowptr[gw + 1];
    for (; j + 4 <= end; j += 4) {
        int s0 = col[j], s1 = col[j + 1], s2 = col[j + 2], s3 = col[j + 3];
        u32 u0 = hb[(size_t)s0 * 64 + lane];
        u32 u1 = hb[(size_t)s1 * 64 + lane];
        u32 u2 = hb[(size_t)s2 * 64 + lane];
        u32 u3 = hb[(size_t)s3 * 64 + lane];
        ax += (bflo(u0) + bflo(u1)) + (bflo(u2) + bflo(u3));
        ay += (bfhi(u0) + bfhi(u1)) + (bfhi(u2) + bfhi(u3));
    }
    for (; j < end; ++j) {
        int s = col[j];
        u32 u = hb[(size_t)s * 64 + lane];
        ax += bflo(u);
        ay += bfhi(u);
    }
    aggb[rowbase + lane] = pack2bf(ax * inv_n, ay * inv_n);
}

// ---------------- MFMA GEMM:  O = relu(A @ W) + R, optional bf16 writeback ----------
// A: [n,128] bf16 (packed u32 pairs). Wt: [128,128] bf16, Wt[c][k] = W[k][c].
// One wave per 16-row tile; 8 col-tiles of 16; K=128 via 4x mfma_f32_16x16x32_bf16.
// Frag layout: A/B = 8 contiguous bf16 at [lane&15][(lane>>4)*8]; D: col=lane&15,
// row=(lane>>4)*4+reg (verified mapping).
template <int WRITE_BF16>
__global__ __launch_bounds__(256) void gemm_mfma(const u32* __restrict__ Ab,
                                                 const u16* __restrict__ Wt,
                                                 const float* __restrict__ R,
                                                 const float* __restrict__ invs,
                                                 float* __restrict__ O,
                                                 u16* __restrict__ hb, int n) {
    int wid = threadIdx.x >> 6;
    int lane = threadIdx.x & 63;
    int rt = blockIdx.x * 4 + wid;  // row-tile
    int r0 = rt * 16;
    if (r0 >= n) return;
    int lm = lane & 15;
    int lk = lane >> 4;

    const u16* Abase = (const u16*)Ab;
    int arow = r0 + lm;
    if (arow >= n) arow = n - 1;
    const u16* ap = Abase + (size_t)arow * 128 + lk * 8;
    bf16x8 a0 = *(const bf16x8*)(ap);
    bf16x8 a1 = *(const bf16x8*)(ap + 32);
    bf16x8 a2 = *(const bf16x8*)(ap + 64);
    bf16x8 a3 = *(const bf16x8*)(ap + 96);

    int drow0 = r0 + lk * 4;
    float iv[4];
    if (WRITE_BF16) {
#pragma unroll
        for (int i = 0; i < 4; ++i) {
            int row = drow0 + i;
            iv[i] = invs[row < n ? row : n - 1];
        }
    }

    for (int ct = 0; ct < 8; ++ct) {
        const u16* bp = Wt + ((ct * 16 + lm) << 7) + lk * 8;
        bf16x8 b0 = *(const bf16x8*)(bp);
        bf16x8 b1 = *(const bf16x8*)(bp + 32);
        bf16x8 b2 = *(const bf16x8*)(bp + 64);
        bf16x8 b3 = *(const bf16x8*)(bp + 96);
        f32x4 acc = {0.f, 0.f, 0.f, 0.f};
        acc = __builtin_amdgcn_mfma_f32_16x16x32_bf16(a0, b0, acc, 0, 0, 0);
        acc = __builtin_amdgcn_mfma_f32_16x16x32_bf16(a1, b1, acc, 0, 0, 0);
        acc = __builtin_amdgcn_mfma_f32_16x16x32_bf16(a2, b2, acc, 0, 0, 0);
        acc = __builtin_amdgcn_mfma_f32_16x16x32_bf16(a3, b3, acc, 0, 0, 0);
        int colc = ct * 16 + lm;
#pragma unroll
        for (int i = 0; i < 4; ++i) {
            int row = drow0 + i;
            if (row < n) {
                size_t off = ((size_t)row << 7) + colc;
                float v = acc[i];
                v = v > 0.f ? v : 0.f;
                v += R[off];
                O[off] = v;
                if (WRITE_BF16) hb[off] = f2bf(v * iv[i]);
            }
        }
    }
}

// ---------------- seed gather ----------------
__global__ void gather_seeds(const int* __restrict__ seeds, const float* __restrict__ ent,
                             float* __restrict__ out, int S) {
    int idx = blockIdx.x * 256 + threadIdx.x;
    if (idx < S * 32) {
        int i = idx >> 5;
        int t = idx & 31;
        int s = seeds[i];
        ((float4*)out)[(size_t)i * 32 + t] = ((const float4*)ent)[(size_t)s * 32 + t];
    }
}

// ---------------- per-graph driver ----------------
static void run_graph(const int* edges, const float* emb, const u16* Wt0, const u16* Wt1,
                      float* ent_out, u32* hb, u32* aggb, int* hist, u32* pairs, int* hsc,
                      float* invs, int* rowptr, int* colb, int* bsums, int N, int E, int NB,
                      hipStream_t stream) {
    int chunk = (((E + NWG - 1) / NWG) + 3) & ~3;
    int M = NB * NWG;
    int sblk = (M + 255) / 256;

    pass1_hist<<<NWG, 256, 0, stream>>>(edges, E, chunk, hist, NB);
    scan_block<<<sblk, 256, 0, stream>>>(hist, hsc, bsums, M);
    scan_bsums<<<1, 512, 0, stream>>>(bsums, sblk);
    add_offsets2<<<sblk, 256, 0, stream>>>(hsc, bsums, M);
    pass2_scatter<<<NWG, 256, 0, stream>>>(edges, E, chunk, hsc, pairs, NB);
    finalize_bucket<<<NB, 256, 0, stream>>>(pairs, hsc, rowptr, invs, colb, N, NB, 2 * E);

    int cb = (N * 64 + 255) / 256;
    int pb = (N + 3) / 4;
    int RT = (N + 15) / 16;
    int gb = (RT + 3) / 4;  // 4 waves (row-tiles) per block

    cast_scale_bf16<<<cb, 256, 0, stream>>>(emb, invs, hb, N * 64);
    pull_agg<<<pb, 256, 0, stream>>>(emb, hb, rowptr, colb, invs, aggb, N);
    gemm_mfma<1><<<gb, 256, 0, stream>>>(aggb, Wt0, emb, invs, ent_out, (u16*)hb, N);
    pull_agg<<<pb, 256, 0, stream>>>(ent_out, hb, rowptr, colb, invs, aggb, N);
    gemm_mfma<0><<<gb, 256, 0, stream>>>(aggb, Wt1, ent_out, invs, ent_out, nullptr, N);
}

extern "C" void kernel_launch(void* const* d_in, const int* in_sizes, int n_in,
                              void* d_out, int out_size, void* d_ws, size_t ws_size,
                              hipStream_t stream) {
    const int* seeds_sr = (const int*)d_in[0];
    const int* seeds_tg = (const int*)d_in[1];
    const int* edges_sr = (const int*)d_in[2];
    const int* edges_tg = (const int*)d_in[3];
    const float* emb_sr = (const float*)d_in[4];
    const float* emb_tg = (const float*)d_in[5];
    const float* W0 = (const float*)d_in[6];
    const float* W1 = (const float*)d_in[7];

    int S = in_sizes[0];
    int E = in_sizes[2] / 2;
    int N = in_sizes[4] / D;
    int NB = (N + 255) / 256;

    float* out = (float*)d_out;
    float* out_sr_seed = out;
    float* out_tg_seed = out + (size_t)S * D;
    float* out_sr_ent = out + 2 * (size_t)S * D;
    float* out_tg_ent = out_sr_ent + (size_t)N * D;

    // workspace carve-up (aliases commented with lifetime proofs)
    char* w = (char*)d_ws;
    u32* hb = (u32*)w;   w += (size_t)N * 64 * 4;  // 25.6MB bf16 gather source
    u32* aggb = (u32*)w; w += (size_t)N * 64 * 4;  // 25.6MB bf16 aggregate
    // hist aliases hb: hist dead after scan_block; hb first written by cast_scale (later)
    int* hist = (int*)hb;
    // pairs + hsc alias aggb (disjoint offsets): both dead before pull_agg writes aggb
    u32* pairs = aggb;                    // 2E*4 = 12.8MB < 16MB
    int* hsc = (int*)(aggb + (1 << 22));  // +16MB; NB*NWG*4 ~ 0.4MB
    float* invs = (float*)w;  w += (size_t)N * 4;
    int* rowptr = (int*)w;    w += (size_t)(N + 64) * 4;
    int* colb = (int*)w;      w += (size_t)2 * E * 4;  // 12.8MB
    int* bsums = (int*)w;     w += 4096;               // <=512 ints used
    u16* Wt0 = (u16*)w;       w += 128 * 128 * 2;
    u16* Wt1 = (u16*)w;       w += 128 * 128 * 2;

    transpose_cast_w<<<64, 256, 0, stream>>>(W0, Wt0);
    transpose_cast_w<<<64, 256, 0, stream>>>(W1, Wt1);

    run_graph(edges_sr, emb_sr, Wt0, Wt1, out_sr_ent, hb, aggb, hist, pairs, hsc, invs,
              rowptr, colb, bsums, N, E, NB, stream);
    run_graph(edges_tg, emb_tg, Wt0, Wt1, out_tg_ent, hb, aggb, hist, pairs, hsc, invs,
              rowptr, colb, bsums, N, E, NB, stream);

    int sb = (S * 32 + 255) / 256;
    gather_seeds<<<sb, 256, 0, stream>>>(seeds_sr, out_sr_ent, out_sr_seed, S);
    gather_seeds<<<sb, 256, 0, stream>>>(seeds_tg, out_tg_ent, out_tg_seed, S);
}

// Round 11
// 903.105 us; speedup vs baseline: 3.2435x; 1.0825x over previous
//
#include <hip/hip_runtime.h>

#define D 128
#define NWG 256  // workgroups for the two edge passes

typedef unsigned int u32;
typedef unsigned short u16;
typedef unsigned char u8;
typedef __attribute__((ext_vector_type(8))) short bf16x8;
typedef __attribute__((ext_vector_type(4))) float f32x4;

__device__ __forceinline__ float bflo(u32 u) { return __uint_as_float(u << 16); }
__device__ __forceinline__ float bfhi(u32 u) { return __uint_as_float(u & 0xffff0000u); }
__device__ __forceinline__ u16 f2bf(float x) {
    u32 u = __float_as_uint(x);
    u = (u + 0x7fffu + ((u >> 16) & 1u)) >> 16;  // round-to-nearest-even
    return (u16)u;
}
__device__ __forceinline__ u32 pack2bf(float a, float b) {
    return (u32)f2bf(a) | ((u32)f2bf(b) << 16);
}
// fp8 e4m3 (OCP) pack/unpack via gfx950 HW converts
__device__ __forceinline__ u32 pack2fp8(float a, float b) {
    return (u32)__builtin_amdgcn_cvt_pk_fp8_f32(a, b, 0, false);
}
__device__ __forceinline__ float2 unpack2fp8(u32 w) {
    auto d = __builtin_amdgcn_cvt_pk_f32_fp8(w, false);  // low 2 bytes
    return make_float2(d[0], d[1]);
}

// ---------------- pass 1: per-(bucket, block) histogram via LDS atomics ----------------
__global__ __launch_bounds__(256) void pass1_hist(const int* __restrict__ e, int E, int chunk,
                                                  int* __restrict__ hist, int NB) {
    __shared__ int lcnt[512];
    int w = blockIdx.x, tid = threadIdx.x;
    for (int b = tid; b < NB; b += 256) lcnt[b] = 0;
    __syncthreads();
    int beg = w * chunk;
    int end = min(E, beg + chunk);
    if (beg < end) {
        int n4 = (end - beg) >> 2;
        for (int g = tid; g < n4; g += 256) {
            int i = beg + g * 4;
            int4 us = *(const int4*)(e + i);
            int4 vs = *(const int4*)(e + E + i);
            atomicAdd(&lcnt[us.x >> 8], 1);
            atomicAdd(&lcnt[vs.x >> 8], 1);
            atomicAdd(&lcnt[us.y >> 8], 1);
            atomicAdd(&lcnt[vs.y >> 8], 1);
            atomicAdd(&lcnt[us.z >> 8], 1);
            atomicAdd(&lcnt[vs.z >> 8], 1);
            atomicAdd(&lcnt[us.w >> 8], 1);
            atomicAdd(&lcnt[vs.w >> 8], 1);
        }
        for (int i = beg + n4 * 4 + tid; i < end; i += 256) {
            atomicAdd(&lcnt[e[i] >> 8], 1);
            atomicAdd(&lcnt[e[E + i] >> 8], 1);
        }
    }
    __syncthreads();
    for (int b = tid; b < NB; b += 256) hist[b * NWG + w] = lcnt[b];
}

// ---------------- exclusive scan (2-level) ----------------
__global__ void scan_block(const int* __restrict__ cnt, int* __restrict__ excl,
                           int* __restrict__ bsums, int n) {
    __shared__ int sm[256];
    int i = blockIdx.x * 256 + threadIdx.x;
    int v = (i < n) ? cnt[i] : 0;
    sm[threadIdx.x] = v;
    __syncthreads();
    for (int off = 1; off < 256; off <<= 1) {
        int t = (threadIdx.x >= off) ? sm[threadIdx.x - off] : 0;
        __syncthreads();
        sm[threadIdx.x] += t;
        __syncthreads();
    }
    if (i < n) excl[i] = sm[threadIdx.x] - v;
    if (threadIdx.x == 255) bsums[blockIdx.x] = sm[255];
}

__global__ void scan_bsums(int* __restrict__ bsums, int nb) {
    __shared__ int sm[512];
    int t = threadIdx.x;
    int v = (t < nb) ? bsums[t] : 0;
    sm[t] = v;
    __syncthreads();
    for (int off = 1; off < 512; off <<= 1) {
        int x = (t >= off) ? sm[t - off] : 0;
        __syncthreads();
        sm[t] += x;
        __syncthreads();
    }
    if (t < nb) bsums[t] = sm[t] - v;  // exclusive
}

__global__ void add_offsets2(int* __restrict__ data, const int* __restrict__ bsums, int n) {
    int i = blockIdx.x * 256 + threadIdx.x;
    if (i < n) data[i] += bsums[blockIdx.x];
}

// ---------------- pass 2: deterministic scatter via LDS bump cursors ----------------
__global__ __launch_bounds__(256) void pass2_scatter(const int* __restrict__ e, int E,
                                                     int chunk, const int* __restrict__ hsc,
                                                     u32* __restrict__ pairs, int NB) {
    __shared__ int lbase[512];
    int w = blockIdx.x, tid = threadIdx.x;
    for (int b = tid; b < NB; b += 256) lbase[b] = hsc[b * NWG + w];
    __syncthreads();
    int beg = w * chunk;
    int end = min(E, beg + chunk);
    if (beg >= end) return;
    auto emit = [&](int dstn, int srcn) {
        int b = dstn >> 8;
        int pos = atomicAdd(&lbase[b], 1);
        pairs[pos] = ((u32)(dstn & 255) << 24) | (u32)srcn;
    };
    int n4 = (end - beg) >> 2;
    for (int g = tid; g < n4; g += 256) {
        int i = beg + g * 4;
        int4 us = *(const int4*)(e + i);
        int4 vs = *(const int4*)(e + E + i);
        emit(us.x, vs.x); emit(vs.x, us.x);
        emit(us.y, vs.y); emit(vs.y, us.y);
        emit(us.z, vs.z); emit(vs.z, us.z);
        emit(us.w, vs.w); emit(vs.w, us.w);
    }
    for (int i = beg + n4 * 4 + tid; i < end; i += 256) {
        int u = e[i], v = e[E + i];
        emit(v, u);
        emit(u, v);
    }
}

// ---------------- finalize: one block per 256-node bucket (contiguous range) ----------
__global__ __launch_bounds__(256) void finalize_bucket(const u32* __restrict__ pairs,
                                                       const int* __restrict__ hsc,
                                                       int* __restrict__ rowptr,
                                                       float* __restrict__ invs,
                                                       int* __restrict__ col, int N, int NB,
                                                       int total) {
    __shared__ int lcnt[256];
    __shared__ int lofs[256];
    int b = blockIdx.x, tid = threadIdx.x;
    int start = hsc[b * NWG];
    int end = (b + 1 < NB) ? hsc[(b + 1) * NWG] : total;
    lcnt[tid] = 0;
    __syncthreads();
    for (int k = start + tid; k < end; k += 256) atomicAdd(&lcnt[pairs[k] >> 24], 1);
    __syncthreads();
    int v = lcnt[tid];
    lofs[tid] = v;
    __syncthreads();
    for (int off = 1; off < 256; off <<= 1) {
        int t2 = (tid >= off) ? lofs[tid - off] : 0;
        __syncthreads();
        lofs[tid] += t2;
        __syncthreads();
    }
    int mystart = start + lofs[tid] - v;
    int node = (b << 8) + tid;
    if (node < N) {
        rowptr[node] = mystart;
        invs[node] = rsqrtf((float)(v + 1));  // +1 self loop
    }
    if (b == NB - 1 && tid == 0) rowptr[N] = total;
    lofs[tid] = mystart;  // reuse as per-node cursor
    __syncthreads();
    for (int k = start + tid; k < end; k += 256) {
        u32 wv = pairs[k];
        int pos = atomicAdd(&lofs[wv >> 24], 1);
        col[pos] = (int)(wv & 0x00FFFFFFu);
    }
}

// ---------------- cast + pre-scale to fp8: hf8[r][c] = fp8(h[r][c] * invs[r]) --------
__global__ void cast_scale_fp8(const float* __restrict__ h, const float* __restrict__ invs,
                               u32* __restrict__ hf8, int n32) {
    int idx = blockIdx.x * 256 + threadIdx.x;  // one u32 = 4 fp8 features
    if (idx >= n32) return;
    int row = idx >> 5;
    float is = invs[row];
    float4 v = ((const float4*)h)[idx];
    u32 lo = pack2fp8(v.x * is, v.y * is);
    u32 p = (u32)__builtin_amdgcn_cvt_pk_fp8_f32(v.z * is, v.w * is, (int)lo, true);
    hf8[idx] = p;
}

// ---------------- W -> bf16 transposed (Wt[c][k] = bf16(W[k][c])) ----------------
__global__ void transpose_cast_w(const float* __restrict__ W, u16* __restrict__ Wt) {
    int idx = blockIdx.x * 256 + threadIdx.x;  // 64 blocks x 256 = 16384
    int k = idx >> 7, c = idx & 127;
    Wt[c * 128 + k] = f2bf(W[idx]);
}

// ---------------- pull aggregation: one wave per node, fp8 pre-scaled gather --------
// hf8 rows hold h*inv (own scale). out = (self + sum_nb) * inv_n, packed bf16.
__global__ __launch_bounds__(256) void pull_agg(const u16* __restrict__ hf8,
                                                const int* __restrict__ rowptr,
                                                const int* __restrict__ col,
                                                const float* __restrict__ invs,
                                                u32* __restrict__ aggb, int n) {
    int gw = (blockIdx.x * 256 + threadIdx.x) >> 6;  // global wave id = node
    if (gw >= n) return;
    int lane = threadIdx.x & 63;
    float inv_n = invs[gw];
    // self term: stored value is already h_self * inv_n
    float2 s0 = unpack2fp8((u32)hf8[(size_t)gw * 64 + lane]);
    float ax = s0.x;
    float ay = s0.y;
    int j = rowptr[gw];
    int end = rowptr[gw + 1];
    for (; j + 4 <= end; j += 4) {
        int i0 = col[j], i1 = col[j + 1], i2 = col[j + 2], i3 = col[j + 3];
        u32 w0 = hf8[(size_t)i0 * 64 + lane];
        u32 w1 = hf8[(size_t)i1 * 64 + lane];
        u32 w2 = hf8[(size_t)i2 * 64 + lane];
        u32 w3 = hf8[(size_t)i3 * 64 + lane];
        float2 d0 = unpack2fp8(w0);
        float2 d1 = unpack2fp8(w1);
        float2 d2 = unpack2fp8(w2);
        float2 d3 = unpack2fp8(w3);
        ax += (d0.x + d1.x) + (d2.x + d3.x);
        ay += (d0.y + d1.y) + (d2.y + d3.y);
    }
    for (; j < end; ++j) {
        int s = col[j];
        float2 d = unpack2fp8((u32)hf8[(size_t)s * 64 + lane]);
        ax += d.x;
        ay += d.y;
    }
    aggb[(size_t)gw * 64 + lane] = pack2bf(ax * inv_n, ay * inv_n);
}

// ---------------- MFMA GEMM:  O = relu(A @ W) + R, optional fp8 writeback ----------
// A: [n,128] bf16 (packed u32 pairs). Wt: [128,128] bf16, Wt[c][k] = W[k][c].
// One wave per 16-row tile; 8 col-tiles of 16; K=128 via 4x mfma_f32_16x16x32_bf16.
// Frag layout: A/B = 8 contiguous bf16 at [lane&15][(lane>>4)*8]; D: col=lane&15,
// row=(lane>>4)*4+reg (verified mapping).
template <int WRITE_FP8>
__global__ __launch_bounds__(256) void gemm_mfma(const u32* __restrict__ Ab,
                                                 const u16* __restrict__ Wt,
                                                 const float* __restrict__ R,
                                                 const float* __restrict__ invs,
                                                 float* __restrict__ O,
                                                 u8* __restrict__ hf8, int n) {
    int wid = threadIdx.x >> 6;
    int lane = threadIdx.x & 63;
    int rt = blockIdx.x * 4 + wid;  // row-tile
    int r0 = rt * 16;
    if (r0 >= n) return;
    int lm = lane & 15;
    int lk = lane >> 4;

    const u16* Abase = (const u16*)Ab;
    int arow = r0 + lm;
    if (arow >= n) arow = n - 1;
    const u16* ap = Abase + (size_t)arow * 128 + lk * 8;
    bf16x8 a0 = *(const bf16x8*)(ap);
    bf16x8 a1 = *(const bf16x8*)(ap + 32);
    bf16x8 a2 = *(const bf16x8*)(ap + 64);
    bf16x8 a3 = *(const bf16x8*)(ap + 96);

    int drow0 = r0 + lk * 4;
    float iv[4];
    if (WRITE_FP8) {
#pragma unroll
        for (int i = 0; i < 4; ++i) {
            int row = drow0 + i;
            iv[i] = invs[row < n ? row : n - 1];
        }
    }

    for (int ct = 0; ct < 8; ++ct) {
        const u16* bp = Wt + ((ct * 16 + lm) << 7) + lk * 8;
        bf16x8 b0 = *(const bf16x8*)(bp);
        bf16x8 b1 = *(const bf16x8*)(bp + 32);
        bf16x8 b2 = *(const bf16x8*)(bp + 64);
        bf16x8 b3 = *(const bf16x8*)(bp + 96);
        f32x4 acc = {0.f, 0.f, 0.f, 0.f};
        acc = __builtin_amdgcn_mfma_f32_16x16x32_bf16(a0, b0, acc, 0, 0, 0);
        acc = __builtin_amdgcn_mfma_f32_16x16x32_bf16(a1, b1, acc, 0, 0, 0);
        acc = __builtin_amdgcn_mfma_f32_16x16x32_bf16(a2, b2, acc, 0, 0, 0);
        acc = __builtin_amdgcn_mfma_f32_16x16x32_bf16(a3, b3, acc, 0, 0, 0);
        int colc = ct * 16 + lm;
#pragma unroll
        for (int i = 0; i < 4; ++i) {
            int row = drow0 + i;
            if (row < n) {
                size_t off = ((size_t)row << 7) + colc;
                float v = acc[i];
                v = v > 0.f ? v : 0.f;
                v += R[off];
                O[off] = v;
                if (WRITE_FP8) {
                    int p = __builtin_amdgcn_cvt_pk_fp8_f32(v * iv[i], v * iv[i], 0, false);
                    hf8[off] = (u8)(p & 0xff);
                }
            }
        }
    }
}

// ---------------- seed gather ----------------
__global__ void gather_seeds(const int* __restrict__ seeds, const float* __restrict__ ent,
                             float* __restrict__ out, int S) {
    int idx = blockIdx.x * 256 + threadIdx.x;
    if (idx < S * 32) {
        int i = idx >> 5;
        int t = idx & 31;
        int s = seeds[i];
        ((float4*)out)[(size_t)i * 32 + t] = ((const float4*)ent)[(size_t)s * 32 + t];
    }
}

// ---------------- per-graph driver ----------------
static void run_graph(const int* edges, const float* emb, const u16* Wt0, const u16* Wt1,
                      float* ent_out, u32* hf8, u32* aggb, int* hist, u32* pairs, int* hsc,
                      float* invs, int* rowptr, int* colb, int* bsums, int N, int E, int NB,
                      hipStream_t stream) {
    int chunk = (((E + NWG - 1) / NWG) + 3) & ~3;
    int M = NB * NWG;
    int sblk = (M + 255) / 256;

    pass1_hist<<<NWG, 256, 0, stream>>>(edges, E, chunk, hist, NB);
    scan_block<<<sblk, 256, 0, stream>>>(hist, hsc, bsums, M);
    scan_bsums<<<1, 512, 0, stream>>>(bsums, sblk);
    add_offsets2<<<sblk, 256, 0, stream>>>(hsc, bsums, M);
    pass2_scatter<<<NWG, 256, 0, stream>>>(edges, E, chunk, hsc, pairs, NB);
    finalize_bucket<<<NB, 256, 0, stream>>>(pairs, hsc, rowptr, invs, colb, N, NB, 2 * E);

    int cb = (N * 32 + 255) / 256;
    int pb = (N + 3) / 4;
    int RT = (N + 15) / 16;
    int gb = (RT + 3) / 4;  // 4 waves (row-tiles) per block

    cast_scale_fp8<<<cb, 256, 0, stream>>>(emb, invs, hf8, N * 32);
    pull_agg<<<pb, 256, 0, stream>>>((const u16*)hf8, rowptr, colb, invs, aggb, N);
    gemm_mfma<1><<<gb, 256, 0, stream>>>(aggb, Wt0, emb, invs, ent_out, (u8*)hf8, N);
    pull_agg<<<pb, 256, 0, stream>>>((const u16*)hf8, rowptr, colb, invs, aggb, N);
    gemm_mfma<0><<<gb, 256, 0, stream>>>(aggb, Wt1, ent_out, invs, ent_out, nullptr, N);
}

extern "C" void kernel_launch(void* const* d_in, const int* in_sizes, int n_in,
                              void* d_out, int out_size, void* d_ws, size_t ws_size,
                              hipStream_t stream) {
    const int* seeds_sr = (const int*)d_in[0];
    const int* seeds_tg = (const int*)d_in[1];
    const int* edges_sr = (const int*)d_in[2];
    const int* edges_tg = (const int*)d_in[3];
    const float* emb_sr = (const float*)d_in[4];
    const float* emb_tg = (const float*)d_in[5];
    const float* W0 = (const float*)d_in[6];
    const float* W1 = (const float*)d_in[7];

    int S = in_sizes[0];
    int E = in_sizes[2] / 2;
    int N = in_sizes[4] / D;
    int NB = (N + 255) / 256;

    float* out = (float*)d_out;
    float* out_sr_seed = out;
    float* out_tg_seed = out + (size_t)S * D;
    float* out_sr_ent = out + 2 * (size_t)S * D;
    float* out_tg_ent = out_sr_ent + (size_t)N * D;

    // workspace carve-up (aliases commented with lifetime proofs)
    char* w = (char*)d_ws;
    u32* hf8 = (u32*)w;  w += (size_t)N * 128;      // 12.8MB fp8 gather source
    u32* aggb = (u32*)w; w += (size_t)N * 64 * 4;   // 25.6MB bf16 aggregate
    // hist aliases hf8: hist dead after scan_block; hf8 first written by cast_scale (later)
    int* hist = (int*)hf8;
    // pairs + hsc alias aggb (disjoint offsets): both dead before pull_agg writes aggb
    u32* pairs = aggb;                    // 2E*4 = 12.8MB < 16MB
    int* hsc = (int*)(aggb + (1 << 22));  // +16MB; NB*NWG*4 ~ 0.4MB
    float* invs = (float*)w;  w += (size_t)N * 4;
    int* rowptr = (int*)w;    w += (size_t)(N + 64) * 4;
    int* colb = (int*)w;      w += (size_t)2 * E * 4;  // 12.8MB
    int* bsums = (int*)w;     w += 4096;               // <=512 ints used
    u16* Wt0 = (u16*)w;       w += 128 * 128 * 2;
    u16* Wt1 = (u16*)w;       w += 128 * 128 * 2;

    transpose_cast_w<<<64, 256, 0, stream>>>(W0, Wt0);
    transpose_cast_w<<<64, 256, 0, stream>>>(W1, Wt1);

    run_graph(edges_sr, emb_sr, Wt0, Wt1, out_sr_ent, hf8, aggb, hist, pairs, hsc, invs,
              rowptr, colb, bsums, N, E, NB, stream);
    run_graph(edges_tg, emb_tg, Wt0, Wt1, out_tg_ent, hf8, aggb, hist, pairs, hsc, invs,
              rowptr, colb, bsums, N, E, NB, stream);

    int sb = (S * 32 + 255) / 256;
    gather_seeds<<<sb, 256, 0, stream>>>(seeds_sr, out_sr_ent, out_sr_seed, S);
    gather_seeds<<<sb, 256, 0, stream>>>(seeds_tg, out_tg_ent, out_tg_seed, S);
}